// Round 10
// baseline (415.636 us; speedup 1.0000x reference)
//
#include <hip/hip_runtime.h>
#include <hip/hip_bf16.h>
#include <cstdint>
#include <cstddef>

#define BQ 128        // queries (problem-fixed)
#define DK 192        // SIG_DIM
#define KTOP 32
#define CHI 64        // gallery items per chunk
#define SLOTS 4       // candidate slots per (query, chunk)
#define QCAP 512      // per-chunk LDS rescore queue
#define OCAP 65536    // global overflow list
#define MARGIN 0.02f  // > 2x (trunc-G + rne-Q) dot error bound (~0.012)
#define TROW 384      // LDS bytes per staged G row (192 bf16, XOR-swizzled 16B blocks)
#define THRV 3200     // thr32 LDS value slots
#define GRIDP 512     // persistent blocks for score_pass

#define NEG_INF (-__builtin_huge_valf())

typedef short short8v __attribute__((ext_vector_type(8)));
typedef float f32x16  __attribute__((ext_vector_type(16)));

__device__ __forceinline__ unsigned fkey(float s) {
    unsigned u = __float_as_uint(s);
    return (u & 0x80000000u) ? ~u : (u | 0x80000000u);   // monotone f32 -> u32
}
__device__ __forceinline__ bool pri_gt(float s1, int i1, float s2, int i2) {
    return (s1 > s2) || (s1 == s2 && i1 < i2);           // jax top_k stability
}
// pack {bf16_trunc(b) : bf16_trunc(a)} in one v_perm_b32 (high halves)
__device__ __forceinline__ unsigned pk_trunc(float a, float b) {
    return __builtin_amdgcn_perm(__float_as_uint(b), __float_as_uint(a),
                                 0x07060302u);
}
__device__ __forceinline__ unsigned f2bf_rne(float x) {
    unsigned u = __float_as_uint(x);
    unsigned r = u + 0x7FFFu + ((u >> 16) & 1u);
    return r >> 16;
}
__device__ __forceinline__ float dot192(const float* __restrict__ a,
                                        const float* __restrict__ b) {
    float s = 0.f;
    #pragma unroll 8
    for (int k = 0; k < DK; ++k) s = fmaf(a[k], b[k], s);
    return s;
}

// ---------------------------------------------------------------------------
// Pipelined MFMA scoring: persistent blocks, each iterates chunks with
// double-buffered LDS G tiles. Next chunk's G loads + this chunk's mask
// loads issue BEFORE the MFMA loop -> HBM latency hidden under compute.
// mode 0: masked per-(chunk,q) bf16-score max -> gmax[chunk][q]
// mode 1: threshold filter -> LDS queue -> exact fp32 cooperative rescore ->
//         slotted append (LDS counters; global atomics only on overflow)
// ---------------------------------------------------------------------------
__global__ __launch_bounds__(256, 2) void score_pass(
    const float* __restrict__ Qf, const float* __restrict__ G,
    const int* __restrict__ mask, const float* __restrict__ thrm,
    float* __restrict__ gmax,
    int* __restrict__ cnt2, float* __restrict__ cs, int* __restrict__ ci,
    int* __restrict__ ocnt, int* __restrict__ oq, int* __restrict__ og,
    float* __restrict__ osv,
    int Ntot, int NCH, int mode)
{
    __shared__ unsigned char Gl[2][CHI * TROW];  // double-buffered bf16 tiles
    __shared__ float    thrmS[BQ];
    __shared__ unsigned queue[QCAP];
    __shared__ int      lcnt[BQ];
    __shared__ int      qn;

    const int t = threadIdx.x;
    const int w = t >> 6, lane = t & 63;
    const int lo5 = lane & 31, hi = lane >> 5;
    const int qbW = w * 32;

    if (t < BQ) { thrmS[t] = mode ? thrm[t] : 0.f; lcnt[t] = 0; }
    if (t == 0) qn = 0;

    // hoist Q fragments (RNE fp32->bf16 in-register; L2-hot reads)
    uint4 aF[12];
    {
        const float* qp = Qf + (size_t)(qbW + lo5) * DK + hi * 8;
        #pragma unroll
        for (int s = 0; s < 12; ++s) {
            float4 x = *reinterpret_cast<const float4*>(qp + s * 16);
            float4 y = *reinterpret_cast<const float4*>(qp + s * 16 + 4);
            aF[s].x = f2bf_rne(x.x) | (f2bf_rne(x.y) << 16);
            aF[s].y = f2bf_rne(x.z) | (f2bf_rne(x.w) << 16);
            aF[s].z = f2bf_rne(y.x) | (f2bf_rne(y.y) << 16);
            aF[s].w = f2bf_rne(y.z) | (f2bf_rne(y.w) << 16);
        }
    }

    float4 ld[12];   // staging registers (in flight across compute)

    auto STAGE_ISSUE = [&](int chunk) {
        const int cb = chunk * CHI;
        const float4* src = reinterpret_cast<const float4*>(G) + (size_t)cb * 48;
        #pragma unroll
        for (int i = 0; i < 12; ++i) {
            const int F4 = t + i * 256;            // 0..3071
            const int row = F4 / 48;
            float4 v = make_float4(0.f, 0.f, 0.f, 0.f);
            if (cb + row < Ntot) v = src[F4];
            ld[i] = v;
        }
    };
    auto STAGE_WRITE = [&](int buf) {
        #pragma unroll
        for (int i = 0; i < 12; ++i) {
            const int F4 = t + i * 256;
            const int row = F4 / 48, c4 = F4 - row * 48;
            const uint2 p = make_uint2(pk_trunc(ld[i].x, ld[i].y),
                                       pk_trunc(ld[i].z, ld[i].w));
            const int sb = (c4 >> 1) ^ (row & 7);  // XOR-swizzled 16B block
            *reinterpret_cast<uint2*>(Gl[buf] + row * TROW + sb * 16 + (c4 & 1) * 8) = p;
        }
    };

    int c = blockIdx.x;
    int pb = 0;
    if (c < NCH) { STAGE_ISSUE(c); STAGE_WRITE(0); }
    __syncthreads();

    while (c < NCH) {
        const int cb = c * CHI;
        const int cn = c + (int)gridDim.x;
        const bool more = (cn < NCH);
        if (more) STAGE_ISSUE(cn);             // next G tile: loads in flight

        // this chunk's mask loads in flight too (mode 0 reads all of it)
        int mk[16][2];
        if (mode == 0) {
            #pragma unroll
            for (int j = 0; j < 16; ++j) {
                const int row = (j & 3) + 8 * (j >> 2) + 4 * hi;
                const size_t mrow = (size_t)(qbW + row) * (size_t)Ntot;
                #pragma unroll
                for (int st = 0; st < 2; ++st) {
                    const int g = cb + st * 32 + lo5;
                    mk[j][st] = (g < Ntot) ? mask[mrow + g] : 1;
                }
            }
        }

        f32x16 acc[2] = {
            {0,0,0,0,0,0,0,0,0,0,0,0,0,0,0,0}, {0,0,0,0,0,0,0,0,0,0,0,0,0,0,0,0}};
        #pragma unroll
        for (int s = 0; s < 12; ++s) {
            union { uint4 u; short8v v; } au; au.u = aF[s];
            #pragma unroll
            for (int st = 0; st < 2; ++st) {
                const int row = st * 32 + lo5;
                const int blk = (s * 2 + hi) ^ (row & 7);
                union { uint4 u; short8v v; } bu;
                bu.u = *reinterpret_cast<const uint4*>(Gl[pb] + row * TROW + blk * 16);
                acc[st] = __builtin_amdgcn_mfma_f32_32x32x16_bf16(
                    au.v, bu.v, acc[st], 0, 0, 0);
            }
        }

        // C layout (32x32): col(item)=lane&31, row(query)=(j&3)+8*(j>>2)+4*hi
        if (mode == 0) {
            #pragma unroll
            for (int j = 0; j < 16; ++j) {
                const int row = (j & 3) + 8 * (j >> 2) + 4 * hi;
                const int q = qbW + row;
                float m = NEG_INF;
                #pragma unroll
                for (int st = 0; st < 2; ++st)
                    if (!mk[j][st]) m = fmaxf(m, acc[st][j]);
                #pragma unroll
                for (int off = 1; off < 32; off <<= 1)
                    m = fmaxf(m, __shfl_xor(m, off));
                if (lo5 == 0) gmax[(size_t)c * BQ + q] = m;
            }
        } else {
            #pragma unroll
            for (int j = 0; j < 16; ++j) {
                const int row = (j & 3) + 8 * (j >> 2) + 4 * hi;
                const int q = qbW + row;
                const float th = thrmS[q];
                #pragma unroll
                for (int st = 0; st < 2; ++st) {
                    const int g = cb + st * 32 + lo5;
                    const float s = acc[st][j];
                    if (g < Ntot && s >= th) {
                        if (!mask[(size_t)q * (size_t)Ntot + g]) {
                            const int p = atomicAdd(&qn, 1);
                            if (p < QCAP) {
                                queue[p] = ((unsigned)q << 24) | (unsigned)g;
                            } else {   // pathological: inline exact rescore
                                float sx = dot192(Qf + q * DK, G + (size_t)g * DK);
                                const int op = atomicAdd(ocnt, 1);
                                if (op < OCAP) { oq[op] = q; og[op] = g; osv[op] = sx; }
                            }
                        }
                    }
                }
            }
            __syncthreads();
            const int nq = qn < QCAP ? qn : QCAP;
            for (int cc = w; cc < nq; cc += 4) {       // one wave per candidate
                const unsigned pk = queue[cc];
                const int q = pk >> 24, g = pk & 0xFFFFFF;
                const float* qr = Qf + q * DK;
                const float* gr = G + (size_t)g * DK;
                const int k0 = lane * 3;
                float part = qr[k0] * gr[k0];
                part = fmaf(qr[k0 + 1], gr[k0 + 1], part);
                part = fmaf(qr[k0 + 2], gr[k0 + 2], part);
                #pragma unroll
                for (int off = 32; off > 0; off >>= 1)
                    part += __shfl_xor(part, off);
                if (lane == 0) {
                    const int p = atomicAdd(&lcnt[q], 1);
                    if (p < SLOTS) {
                        const size_t o = ((size_t)q * NCH + c) * SLOTS + p;
                        cs[o] = part; ci[o] = g;
                    } else {
                        const int op = atomicAdd(ocnt, 1);
                        if (op < OCAP) { oq[op] = q; og[op] = g; osv[op] = part; }
                    }
                }
            }
            __syncthreads();
            if (t < BQ) {
                int v = lcnt[t]; if (v > SLOTS) v = SLOTS;
                cnt2[(size_t)t * NCH + c] = v;
                lcnt[t] = 0;
            }
            if (t == 0) qn = 0;
            // loop-end barrier separates reset from next chunk's atomics
        }

        if (more) STAGE_WRITE(pb ^ 1);         // implicit vmcnt wait here
        __syncthreads();
        pb ^= 1;
        c = cn;
    }
}

// ---------------------------------------------------------------------------
// thrm[q] = (exact 32nd-largest masked chunk-max, radix select) - MARGIN.
// Valid bound: 32 distinct unmasked witnesses with bf16 score >= thr.
// ---------------------------------------------------------------------------
__global__ __launch_bounds__(256) void thr32(
    const float* __restrict__ gmax, float* __restrict__ thrm, int NCH)
{
    __shared__ float vals[THRV];
    __shared__ int hist[256];
    __shared__ int hscan[256];
    __shared__ int bS, gtS;

    const int q = blockIdx.x;
    const int t = threadIdx.x;
    const int M = NCH < THRV ? NCH : THRV;

    for (int i = t; i < M; i += 256) {
        float m = gmax[(size_t)i * BQ + q];
        for (int j = i + THRV; j < NCH; j += THRV)   // graceful for huge N
            m = fmaxf(m, gmax[(size_t)j * BQ + q]);
        vals[i] = m;
    }
    __syncthreads();

    unsigned prefix = 0, pmask = 0;
    int kneed = KTOP;
    for (int pass = 0; pass < 4; ++pass) {
        const int shift = 24 - pass * 8;
        hist[t] = 0;
        __syncthreads();
        for (int i = t; i < M; i += 256) {
            unsigned k = fkey(vals[i]);
            if ((k & pmask) == prefix) atomicAdd(&hist[(k >> shift) & 255], 1);
        }
        __syncthreads();
        int* src = hist; int* dst = hscan;
        for (int off = 1; off < 256; off <<= 1) {
            int v = src[t] + ((t + off) < 256 ? src[t + off] : 0);
            __syncthreads();
            dst[t] = v;
            __syncthreads();
            int* tmp = src; src = dst; dst = tmp;
        }
        if (src[t] >= kneed && (t == 255 || src[t + 1] < kneed)) {
            bS = t; gtS = (t == 255) ? 0 : src[t + 1];
        }
        __syncthreads();
        kneed -= gtS;
        prefix |= ((unsigned)bS) << shift;
        pmask  |= 0xFFu << shift;
        __syncthreads();
    }
    if (t == 0) {
        unsigned u = (prefix & 0x80000000u) ? (prefix & 0x7FFFFFFFu) : ~prefix;
        thrm[q] = __uint_as_float(u) - MARGIN;
    }
}

// ---------------------------------------------------------------------------
// Exact per-query top-32 over slotted candidates (+overflow): 4-pass radix
// select + collect + tie-breaking tournament (score desc, idx asc).
// out: [0..B*K) = indices (as float); [B*K..2BK) = scores.
// ---------------------------------------------------------------------------
__global__ __launch_bounds__(256) void select_topk(
    const float* __restrict__ cs, const int* __restrict__ ci,
    const int* __restrict__ cnt2,
    const int* __restrict__ ocnt, const int* __restrict__ oq,
    const int* __restrict__ og, const float* __restrict__ osv,
    float* __restrict__ out, int CBLK)
{
    __shared__ int   cntRow[4096];
    __shared__ int   hist[256];
    __shared__ int   hscan[256];
    __shared__ float Ls[256];
    __shared__ int   Li[256];
    __shared__ int   lcnt, nTotS, bS, gtS;
    __shared__ float wrs[4]; __shared__ int wri[4], wrslot[4];

    const int q = blockIdx.x;
    const int t = threadIdx.x;
    const size_t qbase = (size_t)q * CBLK * SLOTS;
    const size_t cbase = (size_t)q * CBLK;
    const int CC = CBLK < 4096 ? CBLK : 4096;
    const int novf0 = *ocnt;
    const int novf = novf0 < OCAP ? novf0 : OCAP;
    const int nslots = CBLK * SLOTS;

    for (int i = t; i < CC; i += 256) cntRow[i] = cnt2[cbase + i];
    if (t == 0) nTotS = 0;
    __syncthreads();
    {
        int part = 0;
        for (int i = t; i < CBLK; i += 256)
            part += (i < 4096) ? cntRow[i] : cnt2[cbase + i];
        for (int i = t; i < novf; i += 256)
            if (oq[i] == q) part++;
        atomicAdd(&nTotS, part);
    }
    __syncthreads();
    const int nTot = nTotS;

    unsigned prefix = 0, pmask = 0;
    int kneed = KTOP;

    if (nTot > KTOP) {
        for (int pass = 0; pass < 4; ++pass) {
            const int shift = 24 - pass * 8;
            hist[t] = 0;
            __syncthreads();
            for (int i = t; i < nslots; i += 256) {
                const int b = i >> 2, sl = i & 3;
                const int cb = (b < 4096) ? cntRow[b] : cnt2[cbase + b];
                if (sl < cb) {
                    unsigned k = fkey(cs[qbase + i]);
                    if ((k & pmask) == prefix)
                        atomicAdd(&hist[(k >> shift) & 255], 1);
                }
            }
            for (int i = t; i < novf; i += 256) {
                if (oq[i] == q) {
                    unsigned k = fkey(osv[i]);
                    if ((k & pmask) == prefix)
                        atomicAdd(&hist[(k >> shift) & 255], 1);
                }
            }
            __syncthreads();
            int* src = hist; int* dst = hscan;
            for (int off = 1; off < 256; off <<= 1) {
                int v = src[t] + ((t + off) < 256 ? src[t + off] : 0);
                __syncthreads();
                dst[t] = v;
                __syncthreads();
                int* tmp = src; src = dst; dst = tmp;
            }
            if (src[t] >= kneed && (t == 255 || src[t + 1] < kneed)) {
                bS = t;
                gtS = (t == 255) ? 0 : src[t + 1];
            }
            __syncthreads();
            const int b = bS;
            kneed -= gtS;
            prefix |= ((unsigned)b) << shift;
            pmask  |= 0xFFu << shift;
            __syncthreads();
        }
    }

    if (t == 0) lcnt = 0;
    __syncthreads();
    const unsigned T = (nTot > KTOP) ? prefix : 0u;
    for (int i = t; i < nslots; i += 256) {
        const int b = i >> 2, sl = i & 3;
        const int cb = (b < 4096) ? cntRow[b] : cnt2[cbase + b];
        if (sl < cb) {
            float s = cs[qbase + i];
            if (fkey(s) >= T) {
                int p = atomicAdd(&lcnt, 1);
                if (p < 256) { Ls[p] = s; Li[p] = ci[qbase + i]; }
            }
        }
    }
    for (int i = t; i < novf; i += 256) {
        if (oq[i] == q) {
            float s = osv[i];
            if (fkey(s) >= T) {
                int p = atomicAdd(&lcnt, 1);
                if (p < 256) { Ls[p] = s; Li[p] = og[i]; }
            }
        }
    }
    __syncthreads();
    const int M = lcnt < 256 ? lcnt : 256;

    const int w = t >> 6, lane = t & 63;
    for (int r = 0; r < KTOP; ++r) {
        float bv = (t < M) ? Ls[t] : NEG_INF;
        int   bi = (t < M) ? Li[t] : 0x7fffffff;
        int   bslot = t;
        #pragma unroll
        for (int off = 32; off > 0; off >>= 1) {
            float ov = __shfl_xor(bv, off);
            int   oi = __shfl_xor(bi, off);
            int   osl = __shfl_xor(bslot, off);
            if (pri_gt(ov, oi, bv, bi)) { bv = ov; bi = oi; bslot = osl; }
        }
        if (lane == 0) { wrs[w] = bv; wri[w] = bi; wrslot[w] = bslot; }
        __syncthreads();
        if (t == 0) {
            float fv = wrs[0]; int fi = wri[0]; int fs = wrslot[0];
            #pragma unroll
            for (int ww = 1; ww < 4; ++ww)
                if (pri_gt(wrs[ww], wri[ww], fv, fi)) {
                    fv = wrs[ww]; fi = wri[ww]; fs = wrslot[ww];
                }
            out[q * KTOP + r]                     = (float)fi;
            out[(size_t)BQ * KTOP + q * KTOP + r] = fv;
            Ls[fs] = NEG_INF; Li[fs] = 0x7fffffff;
        }
        __syncthreads();
    }
}

// ---------------------------------------------------------------------------
extern "C" void kernel_launch(void* const* d_in, const int* in_sizes, int n_in,
                              void* d_out, int out_size, void* d_ws, size_t ws_size,
                              hipStream_t stream)
{
    const float* Qf   = (const float*)d_in[0];
    const float* G    = (const float*)d_in[1];
    const int*   mask = (const int*)d_in[2];
    const int Ntot = in_sizes[1] / DK;                 // 200000

    const int NCH = (Ntot + CHI - 1) / CHI;            // 3125
    const int grid = NCH < GRIDP ? NCH : GRIDP;

    // ws layout (bytes): ~17.5 MB total
    char* w = (char*)d_ws;
    int*   ocnt = (int*)(w + 0);                       // [0,4096) control
    float* thrm = (float*)(w + 4096);                  // 512 B
    float* gmax = (float*)(w + 8192);                  // NCH*128*4 = 1.6 MB
    size_t off = 8192 + (size_t)NCH * BQ * 4;
    off = (off + 255) & ~(size_t)255;
    int*   cnt2 = (int*)(w + off);                     // 128*NCH*4
    off += (size_t)BQ * NCH * 4; off = (off + 255) & ~(size_t)255;
    float* cs   = (float*)(w + off);                   // 128*NCH*SLOTS*4
    off += (size_t)BQ * NCH * SLOTS * 4;
    int*   ci   = (int*)(w + off);
    off += (size_t)BQ * NCH * SLOTS * 4;
    int*   oqv  = (int*)(w + off);   off += (size_t)OCAP * 4;
    int*   ogv  = (int*)(w + off);   off += (size_t)OCAP * 4;
    float* osv  = (float*)(w + off);

    (void)hipMemsetAsync(w, 0, 4096, stream);
    score_pass<<<dim3(grid), dim3(256), 0, stream>>>(  // pass 1: chunk maxima
        Qf, G, mask, thrm, gmax, cnt2, cs, ci, ocnt, oqv, ogv, osv,
        Ntot, NCH, 0);
    thr32<<<dim3(BQ), dim3(256), 0, stream>>>(gmax, thrm, NCH);
    score_pass<<<dim3(grid), dim3(256), 0, stream>>>(  // pass 2: filter+rescore
        Qf, G, mask, thrm, gmax, cnt2, cs, ci, ocnt, oqv, ogv, osv,
        Ntot, NCH, 1);
    select_topk<<<dim3(BQ), dim3(256), 0, stream>>>(
        cs, ci, cnt2, ocnt, oqv, ogv, osv, (float*)d_out, NCH);
}

// Round 11
// 243.425 us; speedup vs baseline: 1.7075x; 1.7075x over previous
//
#include <hip/hip_runtime.h>
#include <hip/hip_bf16.h>
#include <cstdint>
#include <cstddef>

#define BQ 128        // queries (problem-fixed)
#define DK 192        // SIG_DIM
#define KTOP 32
#define CHI 32        // gallery items per chunk (small => low VGPR live state)
#define SLOTS 2       // candidate slots per (query, chunk)
#define QCAP 512      // per-chunk LDS rescore queue
#define OCAP 65536    // global overflow list
#define MARGIN 0.02f  // > 2x (trunc-G + rne-Q) dot error bound (~0.012)
#define TROW 384      // LDS bytes per staged G row (192 bf16, XOR-swizzled 16B blocks)
#define THRV 3200     // thr32 LDS value slots
#define GRIDP 768     // persistent blocks (3/CU) for the filter pass; also = sample count
#define CNTL 6400     // select: LDS-cached per-chunk counts

#define NEG_INF (-__builtin_huge_valf())

typedef short short8v __attribute__((ext_vector_type(8)));
typedef float f32x16  __attribute__((ext_vector_type(16)));

__device__ __forceinline__ unsigned fkey(float s) {
    unsigned u = __float_as_uint(s);
    return (u & 0x80000000u) ? ~u : (u | 0x80000000u);   // monotone f32 -> u32
}
__device__ __forceinline__ bool pri_gt(float s1, int i1, float s2, int i2) {
    return (s1 > s2) || (s1 == s2 && i1 < i2);           // jax top_k stability
}
// pack {bf16_trunc(b) : bf16_trunc(a)} in one v_perm_b32 (high halves)
__device__ __forceinline__ unsigned pk_trunc(float a, float b) {
    return __builtin_amdgcn_perm(__float_as_uint(b), __float_as_uint(a),
                                 0x07060302u);
}
__device__ __forceinline__ unsigned f2bf_rne(float x) {
    unsigned u = __float_as_uint(x);
    unsigned r = u + 0x7FFFu + ((u >> 16) & 1u);
    return r >> 16;
}
__device__ __forceinline__ float dot192(const float* __restrict__ a,
                                        const float* __restrict__ b) {
    float s = 0.f;
    #pragma unroll 8
    for (int k = 0; k < DK; ++k) s = fmaf(a[k], b[k], s);
    return s;
}

// ---------------------------------------------------------------------------
// MFMA scoring pass over 32-item chunks x all 128 queries.
// MODE 0: sampled chunks (1 per block): masked per-(chunk,q) bf16 max -> gmax
// MODE 1: full persistent filter: one-ahead register-staged pipeline,
//         threshold filter -> LDS queue -> exact fp32 rescore -> slotted store
// __launch_bounds__(256,3): VGPR cap 170 > ~130 live => NO SPILLS.
// ---------------------------------------------------------------------------
template<int MODE>
__global__ __launch_bounds__(256, 3) void score_pass(
    const float* __restrict__ Qf, const float* __restrict__ G,
    const int* __restrict__ mask, const float* __restrict__ thrm,
    float* __restrict__ gmax,
    int* __restrict__ cnt2, float* __restrict__ cs, int* __restrict__ ci,
    int* __restrict__ ocnt, int* __restrict__ oq, int* __restrict__ og,
    float* __restrict__ osv,
    int Ntot, int NCH, int SC)
{
    __shared__ unsigned char Gl[2][CHI * TROW];  // double-buffered bf16 tiles
    __shared__ float    thrmS[BQ];
    __shared__ unsigned queue[QCAP];
    __shared__ int      lcnt[BQ];
    __shared__ int      qn;

    const int t = threadIdx.x;
    const int w = t >> 6, lane = t & 63;
    const int lo5 = lane & 31, hi = lane >> 5;
    const int qbW = w * 32;

    if (t < BQ) { thrmS[t] = (MODE == 1) ? thrm[t] : 0.f; lcnt[t] = 0; }
    if (t == 0) qn = 0;

    // hoist Q fragments once per block (RNE fp32->bf16 in-register)
    uint4 aF[12];
    {
        const float* qp = Qf + (size_t)(qbW + lo5) * DK + hi * 8;
        #pragma unroll
        for (int s = 0; s < 12; ++s) {
            float4 x = *reinterpret_cast<const float4*>(qp + s * 16);
            float4 y = *reinterpret_cast<const float4*>(qp + s * 16 + 4);
            aF[s].x = f2bf_rne(x.x) | (f2bf_rne(x.y) << 16);
            aF[s].y = f2bf_rne(x.z) | (f2bf_rne(x.w) << 16);
            aF[s].z = f2bf_rne(y.x) | (f2bf_rne(y.y) << 16);
            aF[s].w = f2bf_rne(y.z) | (f2bf_rne(y.w) << 16);
        }
    }

    // per-thread staging geometry (6 float4 covers 32 rows x 48 float4)
    float4 ld[6];
    int srow[6], sc4[6];
    #pragma unroll
    for (int i = 0; i < 6; ++i) {
        const int f = t + i * 256;
        srow[i] = f / 48; sc4[i] = f - srow[i] * 48;
    }

    auto STAGE_ISSUE = [&](int chunk) {
        const int cb = chunk * CHI;
        const float4* src = reinterpret_cast<const float4*>(G) + (size_t)cb * 48;
        #pragma unroll
        for (int i = 0; i < 6; ++i) {
            float4 v = make_float4(0.f, 0.f, 0.f, 0.f);
            if (cb + srow[i] < Ntot) v = src[t + i * 256];
            ld[i] = v;
        }
    };
    auto STAGE_WRITE = [&](int buf) {
        #pragma unroll
        for (int i = 0; i < 6; ++i) {
            const uint2 p = make_uint2(pk_trunc(ld[i].x, ld[i].y),
                                       pk_trunc(ld[i].z, ld[i].w));
            const int sb = (sc4[i] >> 1) ^ (srow[i] & 7);   // XOR-swizzled block
            *reinterpret_cast<uint2*>(
                Gl[buf] + srow[i] * TROW + sb * 16 + (sc4[i] & 1) * 8) = p;
        }
    };

    const int step0 = (MODE == 0) ? 1 : (int)gridDim.x;      // chunk stride
    int it = blockIdx.x;
    const int itEnd = (MODE == 0) ? (blockIdx.x + 1) : NCH;  // MODE0: 1 chunk
    auto CHUNK_OF = [&](int idx) {
        return (MODE == 0) ? (int)(((long long)idx * NCH) / SC) : idx;
    };

    if (it < itEnd) { STAGE_ISSUE(CHUNK_OF(it)); STAGE_WRITE(0); }
    __syncthreads();
    int pb = 0;

    while (it < itEnd) {
        const int c = CHUNK_OF(it);
        const int cb = c * CHI;
        const int itn = it + step0;
        const bool more = itn < itEnd;
        if (more) STAGE_ISSUE(CHUNK_OF(itn));   // next tile's loads in flight

        f32x16 acc = {0,0,0,0,0,0,0,0,0,0,0,0,0,0,0,0};
        #pragma unroll
        for (int s = 0; s < 12; ++s) {
            union { uint4 u; short8v v; } au; au.u = aF[s];
            const int blk = (s * 2 + hi) ^ (lo5 & 7);
            union { uint4 u; short8v v; } bu;
            bu.u = *reinterpret_cast<const uint4*>(Gl[pb] + lo5 * TROW + blk * 16);
            acc = __builtin_amdgcn_mfma_f32_32x32x16_bf16(au.v, bu.v, acc, 0, 0, 0);
        }

        // C layout (32x32): col(item)=lane&31, row(query)=(j&3)+8*(j>>2)+4*hi
        if (MODE == 0) {
            #pragma unroll
            for (int j = 0; j < 16; ++j) {
                const int row = (j & 3) + 8 * (j >> 2) + 4 * hi;
                const int q = qbW + row;
                const int g = cb + lo5;
                float m = NEG_INF;
                if (g < Ntot && !mask[(size_t)q * (size_t)Ntot + g])
                    m = acc[j];
                #pragma unroll
                for (int off = 1; off < 32; off <<= 1)
                    m = fmaxf(m, __shfl_xor(m, off));
                if (lo5 == 0) gmax[(size_t)it * BQ + q] = m;   // sample index
            }
        } else {
            #pragma unroll
            for (int j = 0; j < 16; ++j) {
                const int row = (j & 3) + 8 * (j >> 2) + 4 * hi;
                const int q = qbW + row;
                const float th = thrmS[q];
                const int g = cb + lo5;
                const float s = acc[j];
                if (g < Ntot && s >= th) {
                    if (!mask[(size_t)q * (size_t)Ntot + g]) {
                        const int p = atomicAdd(&qn, 1);
                        if (p < QCAP) {
                            queue[p] = ((unsigned)q << 24) | (unsigned)g;
                        } else {   // pathological: inline exact rescore
                            float sx = dot192(Qf + q * DK, G + (size_t)g * DK);
                            const int op = atomicAdd(ocnt, 1);
                            if (op < OCAP) { oq[op] = q; og[op] = g; osv[op] = sx; }
                        }
                    }
                }
            }
            __syncthreads();
            const int nq = qn < QCAP ? qn : QCAP;
            for (int cc = w; cc < nq; cc += 4) {       // one wave per candidate
                const unsigned pk = queue[cc];
                const int q = pk >> 24, g = pk & 0xFFFFFF;
                const float* qr = Qf + q * DK;
                const float* gr = G + (size_t)g * DK;
                const int k0 = lane * 3;
                float part = qr[k0] * gr[k0];
                part = fmaf(qr[k0 + 1], gr[k0 + 1], part);
                part = fmaf(qr[k0 + 2], gr[k0 + 2], part);
                #pragma unroll
                for (int off = 32; off > 0; off >>= 1)
                    part += __shfl_xor(part, off);
                if (lane == 0) {
                    const int p = atomicAdd(&lcnt[q], 1);
                    if (p < SLOTS) {
                        const size_t o = ((size_t)q * NCH + c) * SLOTS + p;
                        cs[o] = part; ci[o] = g;
                    } else {
                        const int op = atomicAdd(ocnt, 1);
                        if (op < OCAP) { oq[op] = q; og[op] = g; osv[op] = part; }
                    }
                }
            }
            __syncthreads();
            if (t < BQ) {
                int v = lcnt[t]; if (v > SLOTS) v = SLOTS;
                cnt2[(size_t)t * NCH + c] = v;
                lcnt[t] = 0;
            }
            if (t == 0) qn = 0;
        }

        if (more) STAGE_WRITE(pb ^ 1);   // loads have landed under compute
        __syncthreads();
        pb ^= 1;
        it = itn;
    }
}

// ---------------------------------------------------------------------------
// thrm[q] = (exact 32nd-largest of SC sampled masked chunk-maxima) - MARGIN.
// Valid bound: 32 distinct unmasked witnesses with bf16 score >= thr.
// ---------------------------------------------------------------------------
__global__ __launch_bounds__(256) void thr32(
    const float* __restrict__ gmax, float* __restrict__ thrm, int SC)
{
    __shared__ float vals[THRV];
    __shared__ int hist[256];
    __shared__ int hscan[256];
    __shared__ int bS, gtS;

    const int q = blockIdx.x;
    const int t = threadIdx.x;
    const int M = SC < THRV ? SC : THRV;

    for (int i = t; i < M; i += 256) {
        float m = gmax[(size_t)i * BQ + q];
        for (int j = i + THRV; j < SC; j += THRV)
            m = fmaxf(m, gmax[(size_t)j * BQ + q]);
        vals[i] = m;
    }
    __syncthreads();

    unsigned prefix = 0, pmask = 0;
    int kneed = KTOP;
    for (int pass = 0; pass < 4; ++pass) {
        const int shift = 24 - pass * 8;
        hist[t] = 0;
        __syncthreads();
        for (int i = t; i < M; i += 256) {
            unsigned k = fkey(vals[i]);
            if ((k & pmask) == prefix) atomicAdd(&hist[(k >> shift) & 255], 1);
        }
        __syncthreads();
        int* src = hist; int* dst = hscan;
        for (int off = 1; off < 256; off <<= 1) {
            int v = src[t] + ((t + off) < 256 ? src[t + off] : 0);
            __syncthreads();
            dst[t] = v;
            __syncthreads();
            int* tmp = src; src = dst; dst = tmp;
        }
        if (src[t] >= kneed && (t == 255 || src[t + 1] < kneed)) {
            bS = t; gtS = (t == 255) ? 0 : src[t + 1];
        }
        __syncthreads();
        kneed -= gtS;
        prefix |= ((unsigned)bS) << shift;
        pmask  |= 0xFFu << shift;
        __syncthreads();
    }
    if (t == 0) {
        unsigned u = (prefix & 0x80000000u) ? (prefix & 0x7FFFFFFFu) : ~prefix;
        thrm[q] = __uint_as_float(u) - MARGIN;
    }
}

// ---------------------------------------------------------------------------
// Exact per-query top-32 over slotted candidates (+overflow): 4-pass radix
// select + collect + tie-breaking tournament (score desc, idx asc).
// out: [0..B*K) = indices (as float); [B*K..2BK) = scores.
// ---------------------------------------------------------------------------
__global__ __launch_bounds__(256) void select_topk(
    const float* __restrict__ cs, const int* __restrict__ ci,
    const int* __restrict__ cnt2,
    const int* __restrict__ ocnt, const int* __restrict__ oq,
    const int* __restrict__ og, const float* __restrict__ osv,
    float* __restrict__ out, int CBLK)
{
    __shared__ int   cntRow[CNTL];
    __shared__ int   hist[256];
    __shared__ int   hscan[256];
    __shared__ float Ls[256];
    __shared__ int   Li[256];
    __shared__ int   lcnt, nTotS, bS, gtS;
    __shared__ float wrs[4]; __shared__ int wri[4], wrslot[4];

    const int q = blockIdx.x;
    const int t = threadIdx.x;
    const size_t qbase = (size_t)q * CBLK * SLOTS;
    const size_t cbase = (size_t)q * CBLK;
    const int CC = CBLK < CNTL ? CBLK : CNTL;
    const int novf0 = *ocnt;
    const int novf = novf0 < OCAP ? novf0 : OCAP;
    const int nslots = CBLK * SLOTS;

    for (int i = t; i < CC; i += 256) cntRow[i] = cnt2[cbase + i];
    if (t == 0) nTotS = 0;
    __syncthreads();
    {
        int part = 0;
        for (int i = t; i < CBLK; i += 256)
            part += (i < CNTL) ? cntRow[i] : cnt2[cbase + i];
        for (int i = t; i < novf; i += 256)
            if (oq[i] == q) part++;
        atomicAdd(&nTotS, part);
    }
    __syncthreads();
    const int nTot = nTotS;

    unsigned prefix = 0, pmask = 0;
    int kneed = KTOP;

    if (nTot > KTOP) {
        for (int pass = 0; pass < 4; ++pass) {
            const int shift = 24 - pass * 8;
            hist[t] = 0;
            __syncthreads();
            for (int i = t; i < nslots; i += 256) {
                const int b = i >> 1, sl = i & 1;          // SLOTS = 2
                const int cb = (b < CNTL) ? cntRow[b] : cnt2[cbase + b];
                if (sl < cb) {
                    unsigned k = fkey(cs[qbase + i]);
                    if ((k & pmask) == prefix)
                        atomicAdd(&hist[(k >> shift) & 255], 1);
                }
            }
            for (int i = t; i < novf; i += 256) {
                if (oq[i] == q) {
                    unsigned k = fkey(osv[i]);
                    if ((k & pmask) == prefix)
                        atomicAdd(&hist[(k >> shift) & 255], 1);
                }
            }
            __syncthreads();
            int* src = hist; int* dst = hscan;
            for (int off = 1; off < 256; off <<= 1) {
                int v = src[t] + ((t + off) < 256 ? src[t + off] : 0);
                __syncthreads();
                dst[t] = v;
                __syncthreads();
                int* tmp = src; src = dst; dst = tmp;
            }
            if (src[t] >= kneed && (t == 255 || src[t + 1] < kneed)) {
                bS = t;
                gtS = (t == 255) ? 0 : src[t + 1];
            }
            __syncthreads();
            const int b = bS;
            kneed -= gtS;
            prefix |= ((unsigned)b) << shift;
            pmask  |= 0xFFu << shift;
            __syncthreads();
        }
    }

    if (t == 0) lcnt = 0;
    __syncthreads();
    const unsigned T = (nTot > KTOP) ? prefix : 0u;
    for (int i = t; i < nslots; i += 256) {
        const int b = i >> 1, sl = i & 1;
        const int cb = (b < CNTL) ? cntRow[b] : cnt2[cbase + b];
        if (sl < cb) {
            float s = cs[qbase + i];
            if (fkey(s) >= T) {
                int p = atomicAdd(&lcnt, 1);
                if (p < 256) { Ls[p] = s; Li[p] = ci[qbase + i]; }
            }
        }
    }
    for (int i = t; i < novf; i += 256) {
        if (oq[i] == q) {
            float s = osv[i];
            if (fkey(s) >= T) {
                int p = atomicAdd(&lcnt, 1);
                if (p < 256) { Ls[p] = s; Li[p] = og[i]; }
            }
        }
    }
    __syncthreads();
    const int M = lcnt < 256 ? lcnt : 256;

    const int w = t >> 6, lane = t & 63;
    for (int r = 0; r < KTOP; ++r) {
        float bv = (t < M) ? Ls[t] : NEG_INF;
        int   bi = (t < M) ? Li[t] : 0x7fffffff;
        int   bslot = t;
        #pragma unroll
        for (int off = 32; off > 0; off >>= 1) {
            float ov = __shfl_xor(bv, off);
            int   oi = __shfl_xor(bi, off);
            int   osl = __shfl_xor(bslot, off);
            if (pri_gt(ov, oi, bv, bi)) { bv = ov; bi = oi; bslot = osl; }
        }
        if (lane == 0) { wrs[w] = bv; wri[w] = bi; wrslot[w] = bslot; }
        __syncthreads();
        if (t == 0) {
            float fv = wrs[0]; int fi = wri[0]; int fs = wrslot[0];
            #pragma unroll
            for (int ww = 1; ww < 4; ++ww)
                if (pri_gt(wrs[ww], wri[ww], fv, fi)) {
                    fv = wrs[ww]; fi = wri[ww]; fs = wrslot[ww];
                }
            out[q * KTOP + r]                     = (float)fi;
            out[(size_t)BQ * KTOP + q * KTOP + r] = fv;
            Ls[fs] = NEG_INF; Li[fs] = 0x7fffffff;
        }
        __syncthreads();
    }
}

// ---------------------------------------------------------------------------
extern "C" void kernel_launch(void* const* d_in, const int* in_sizes, int n_in,
                              void* d_out, int out_size, void* d_ws, size_t ws_size,
                              hipStream_t stream)
{
    const float* Qf   = (const float*)d_in[0];
    const float* G    = (const float*)d_in[1];
    const int*   mask = (const int*)d_in[2];
    const int Ntot = in_sizes[1] / DK;                 // 200000

    const int NCH = (Ntot + CHI - 1) / CHI;            // 6250
    const int SC  = GRIDP < NCH ? GRIDP : NCH;         // 768 sampled chunks
    const int grid1 = GRIDP < NCH ? GRIDP : NCH;

    // ws layout (bytes): ~17.2 MB total
    char* w = (char*)d_ws;
    int*   ocnt = (int*)(w + 0);                       // [0,4096) control
    float* thrm = (float*)(w + 4096);                  // 512 B
    float* gmax = (float*)(w + 8192);                  // SC*128*4
    size_t off = 8192 + (size_t)SC * BQ * 4;
    off = (off + 255) & ~(size_t)255;
    int*   cnt2 = (int*)(w + off);                     // 128*NCH*4
    off += (size_t)BQ * NCH * 4; off = (off + 255) & ~(size_t)255;
    float* cs   = (float*)(w + off);                   // 128*NCH*SLOTS*4
    off += (size_t)BQ * NCH * SLOTS * 4;
    int*   ci   = (int*)(w + off);
    off += (size_t)BQ * NCH * SLOTS * 4;
    int*   oqv  = (int*)(w + off);   off += (size_t)OCAP * 4;
    int*   ogv  = (int*)(w + off);   off += (size_t)OCAP * 4;
    float* osv  = (float*)(w + off);

    (void)hipMemsetAsync(w, 0, 4096, stream);
    score_pass<0><<<dim3(SC), dim3(256), 0, stream>>>(      // sampled maxima
        Qf, G, mask, thrm, gmax, cnt2, cs, ci, ocnt, oqv, ogv, osv,
        Ntot, NCH, SC);
    thr32<<<dim3(BQ), dim3(256), 0, stream>>>(gmax, thrm, SC);
    score_pass<1><<<dim3(grid1), dim3(256), 0, stream>>>(   // full filter
        Qf, G, mask, thrm, gmax, cnt2, cs, ci, ocnt, oqv, ogv, osv,
        Ntot, NCH, SC);
    select_topk<<<dim3(BQ), dim3(256), 0, stream>>>(
        cs, ci, cnt2, ocnt, oqv, ogv, osv, (float*)d_out, NCH);
}